// Round 1
// baseline (173.365 us; speedup 1.0000x reference)
//
#include <hip/hip_runtime.h>
#include <math.h>

// ---------------------------------------------------------------------------
// LocalTransformerBlock2d: B=1, C=256, H=W=56 (N=3136), 8 heads x d=32,
// 7x7 local window, dilation 1. fp32 in/out; bf16 MFMA for all GEMMs.
// Pipeline: cvt weights -> LN1+transpose -> qkv GEMM -> local attn ->
//           proj GEMM(+resid) -> LN2 -> fc1 GEMM(+gelu) -> fc2 GEMM(+resid,T)
// ---------------------------------------------------------------------------

typedef unsigned int uint;
typedef unsigned short ushort;
typedef __attribute__((ext_vector_type(8))) short short8;   // 8 bf16 (4 VGPRs)
typedef __attribute__((ext_vector_type(4))) float floatx4;  // MFMA acc
typedef __attribute__((ext_vector_type(4))) unsigned short ushort4v;

#define AS1(p) (const __attribute__((address_space(1))) void*)(p)
#define AS3(p) (__attribute__((address_space(3))) void*)(p)

__device__ __forceinline__ float bf2f(ushort u) {
  union { uint i; float f; } v; v.i = ((uint)u) << 16; return v.f;
}
__device__ __forceinline__ ushort f2bf(float f) {
  union { float f; uint i; } v; v.f = f;
  uint u = v.i;
  return (ushort)((u + 0x7fffu + ((u >> 16) & 1u)) >> 16);
}

// ---------------------------------------------------------------------------
// Weight fp32 -> bf16 (concatenated: qkv_w | proj_w | fc1_w | fc2_w)
// sizes: 196608 | 65536 | 262144 | 262144  (total 786432)
// ---------------------------------------------------------------------------
__global__ __launch_bounds__(256) void cvt_kernel(
    const float* __restrict__ qw, const float* __restrict__ pw,
    const float* __restrict__ f1, const float* __restrict__ f2,
    ushort* __restrict__ out)
{
  int idx = blockIdx.x * 256 + threadIdx.x;
  float v;
  if (idx < 196608)       v = qw[idx];
  else if (idx < 262144)  v = pw[idx - 196608];
  else if (idx < 524288)  v = f1[idx - 262144];
  else                    v = f2[idx - 524288];
  out[idx] = f2bf(v);
}

// ---------------------------------------------------------------------------
// LN1 over channels + transpose [C,N] -> [N,C].
// Block: 16 pixels x 256 channels. Outputs: xT fp32 [N][C], t1 bf16 [N][C].
// ---------------------------------------------------------------------------
__global__ __launch_bounds__(256) void ln1_kernel(
    const float* __restrict__ x, const float* __restrict__ w,
    const float* __restrict__ b, float* __restrict__ xT, ushort* __restrict__ t1)
{
  __shared__ float tile[256 * 17];       // [c][px], pad 17 to dodge conflicts
  __shared__ float red[2][16][16];
  __shared__ float mu[16], rsv[16];
  const int tid = threadIdx.x;
  const int n0 = blockIdx.x * 16;
  const int px = tid & 15, grp = tid >> 4;

  #pragma unroll 4
  for (int it = 0; it < 16; ++it) {
    int c = it * 16 + grp;
    tile[c * 17 + px] = x[(size_t)c * 3136 + n0 + px];   // coalesced along n
  }
  __syncthreads();

  float s = 0.f, ss = 0.f;
  #pragma unroll
  for (int i = 0; i < 16; ++i) {
    float v = tile[(grp * 16 + i) * 17 + px];
    s += v; ss += v * v;
  }
  red[0][px][grp] = s; red[1][px][grp] = ss;
  __syncthreads();
  if (tid < 16) {
    float s2 = 0.f, ss2 = 0.f;
    #pragma unroll
    for (int g = 0; g < 16; ++g) { s2 += red[0][tid][g]; ss2 += red[1][tid][g]; }
    float m = s2 * (1.f / 256.f);
    float var = ss2 * (1.f / 256.f) - m * m;
    mu[tid] = m;
    rsv[tid] = rsqrtf(var + 1e-5f);
  }
  __syncthreads();

  const float wc = w[tid], bc = b[tid];
  #pragma unroll 4
  for (int p = 0; p < 16; ++p) {
    float v = tile[tid * 17 + p];
    xT[(size_t)(n0 + p) * 256 + tid] = v;                       // coalesced
    t1[(size_t)(n0 + p) * 256 + tid] = f2bf((v - mu[p]) * rsv[p] * wc + bc);
  }
}

// ---------------------------------------------------------------------------
// bf16 MFMA GEMM: D[M][N] = A[M][K] @ B[N][K]^T, 64x64 tile, BK=32.
// Both A,B row-major K-contiguous bf16. 4 waves; wave w owns rows [16w,16w+16).
// epi: 0=qkv(+bias, scale q), 1=proj(+bias+resid -> fp32),
//      2=fc1(+bias, gelu -> bf16), 3=fc2(+bias[m]+resid[n*256+m] -> fp32)
// ---------------------------------------------------------------------------
__global__ __launch_bounds__(256) void gemm_kernel(
    const ushort* __restrict__ A, const ushort* __restrict__ B,
    const float* __restrict__ bias, const float* resid,
    ushort* outb, float* outf, int M, int N, int K, int epi)
{
  __shared__ ushort As[64 * 32];
  __shared__ ushort Bs[64 * 32];
  const int tid = threadIdx.x;
  const int lane = tid & 63;
  const int w = tid >> 6;
  const int m0 = blockIdx.y * 64;
  const int n0 = blockIdx.x * 64;

  floatx4 acc[4] = {{0.f,0.f,0.f,0.f},{0.f,0.f,0.f,0.f},
                    {0.f,0.f,0.f,0.f},{0.f,0.f,0.f,0.f}};

  // staging: thread t stages 16B at tile byte offset t*16 (row t/4, col (t&3)*8)
  const int srow = tid >> 2;
  const int scol = (tid & 3) * 8;
  const ushort* Ag = A + (size_t)(m0 + srow) * K + scol;
  const ushort* Bg = B + (size_t)(n0 + srow) * K + scol;
  ushort* Al = As + tid * 8;
  ushort* Bl = Bs + tid * 8;

  const int fm = (lane & 15);       // frag row/col within 16
  const int fk = (lane >> 4) * 8;   // k offset of this lane's quad

  for (int kt = 0; kt < K; kt += 32) {
    __builtin_amdgcn_global_load_lds(AS1(Ag + kt), AS3(Al), 16, 0, 0);
    __builtin_amdgcn_global_load_lds(AS1(Bg + kt), AS3(Bl), 16, 0, 0);
    asm volatile("s_waitcnt vmcnt(0)" ::: "memory");
    __syncthreads();
    short8 af = *(const short8*)&As[(w * 16 + fm) * 32 + fk];
    #pragma unroll
    for (int nt = 0; nt < 4; ++nt) {
      short8 bfr = *(const short8*)&Bs[(nt * 16 + fm) * 32 + fk];
      acc[nt] = __builtin_amdgcn_mfma_f32_16x16x32_bf16(af, bfr, acc[nt], 0, 0, 0);
    }
    __syncthreads();
  }

  // epilogue: elem (nt, r): m = m0+16w+4*(lane>>4)+r, n = n0+16nt+(lane&15)
  const int q4 = (lane >> 4) * 4;
  #pragma unroll
  for (int nt = 0; nt < 4; ++nt) {
    #pragma unroll
    for (int r = 0; r < 4; ++r) {
      int m = m0 + w * 16 + q4 + r;
      int n = n0 + nt * 16 + fm;
      float v = acc[nt][r];
      if (epi == 0) {
        v += bias[n];
        if (n < 256) v *= 0.17677669529663687f;   // 1/sqrt(32) on q
        outb[(size_t)m * N + n] = f2bf(v);
      } else if (epi == 1) {
        v += bias[n] + resid[(size_t)m * N + n];
        outf[(size_t)m * N + n] = v;
      } else if (epi == 2) {
        v += bias[n];
        v = 0.5f * v * (1.0f + erff(v * 0.70710678118654752f));
        outb[(size_t)m * N + n] = f2bf(v);
      } else {
        v += bias[m] + resid[(size_t)n * 256 + m];
        outf[(size_t)m * N + n] = v;   // [C][N] final layout, coalesced in n
      }
    }
  }
}

// ---------------------------------------------------------------------------
// Local attention. Block = one query pixel, 256 threads = 8 heads x 32.
// qkv bf16 [N][768] (q pre-scaled). out bf16 [N][256].
// ---------------------------------------------------------------------------
__global__ __launch_bounds__(256) void attn_kernel(
    const ushort* __restrict__ qkv, ushort* __restrict__ out)
{
  const int n = blockIdx.x;
  const int i = n / 56, j = n % 56;
  const int tid = threadIdx.x;
  const int h = tid >> 5, dd = tid & 31;
  __shared__ float qs[256];
  __shared__ float sc[8][64];
  __shared__ float pr[8][64];

  qs[tid] = bf2f(qkv[(size_t)n * 768 + tid]);
  __syncthreads();

  // scores: thread (h, m-slot), two passes cover m in [0,64)
  #pragma unroll
  for (int p = 0; p < 2; ++p) {
    int m = p * 32 + dd;
    float s = -1e30f;
    if (m < 49) {
      int ii = i + m / 7 - 3;
      int jj = j + m % 7 - 3;
      if (ii >= 0 && ii < 56 && jj >= 0 && jj < 56) {
        const ushort* kp = qkv + (size_t)(ii * 56 + jj) * 768 + 256 + h * 32;
        float a = 0.f;
        #pragma unroll
        for (int u = 0; u < 4; ++u) {
          short8 kv = *(const short8*)(kp + u * 8);
          #pragma unroll
          for (int e = 0; e < 8; ++e)
            a += qs[h * 32 + u * 8 + e] * bf2f((ushort)kv[e]);
        }
        s = a;
      }
    }
    sc[h][m] = s;
  }
  __syncthreads();

  // softmax per head over 49 slots (half-wave shuffle reduce)
  float s0 = sc[h][dd], s1 = sc[h][dd + 32];
  float mx = fmaxf(s0, s1);
  #pragma unroll
  for (int o = 16; o >= 1; o >>= 1) mx = fmaxf(mx, __shfl_xor(mx, o));
  float e0 = __expf(s0 - mx);
  float e1 = __expf(s1 - mx);     // invalid slots were -1e30 -> exp = 0
  float sm = e0 + e1;
  #pragma unroll
  for (int o = 16; o >= 1; o >>= 1) sm += __shfl_xor(sm, o);
  float inv = 1.0f / sm;
  pr[h][dd] = e0 * inv;
  pr[h][dd + 32] = e1 * inv;
  __syncthreads();

  // PV: thread (h, d); loop over valid neighbors (block-uniform branches)
  float accv = 0.f;
  #pragma unroll
  for (int di = -3; di <= 3; ++di) {
    int ii = i + di;
    if (ii < 0 || ii >= 56) continue;
    #pragma unroll
    for (int dj = -3; dj <= 3; ++dj) {
      int jj = j + dj;
      if (jj < 0 || jj >= 56) continue;
      int m = (di + 3) * 7 + (dj + 3);
      float pm = pr[h][m];                                    // LDS broadcast
      float vv = bf2f(qkv[(size_t)(ii * 56 + jj) * 768 + 512 + tid]);  // coalesced
      accv += pm * vv;
    }
  }
  out[(size_t)n * 256 + tid] = f2bf(accv);
}

// ---------------------------------------------------------------------------
// LN2: rows of x1 fp32 [N][256] are contiguous -> one wave per row.
// ---------------------------------------------------------------------------
__global__ __launch_bounds__(256) void ln2_kernel(
    const float* __restrict__ x1, const float* __restrict__ w,
    const float* __restrict__ b, ushort* __restrict__ t2)
{
  const int tid = threadIdx.x;
  const int row = blockIdx.x * 4 + (tid >> 6);
  const int lane = tid & 63;
  floatx4 v = *(const floatx4*)(x1 + (size_t)row * 256 + lane * 4);
  float s = v[0] + v[1] + v[2] + v[3];
  float ss = v[0]*v[0] + v[1]*v[1] + v[2]*v[2] + v[3]*v[3];
  #pragma unroll
  for (int o = 32; o >= 1; o >>= 1) { s += __shfl_xor(s, o); ss += __shfl_xor(ss, o); }
  float m = s * (1.f / 256.f);
  float var = ss * (1.f / 256.f) - m * m;
  float rs = rsqrtf(var + 1e-5f);
  ushort4v o4;
  #pragma unroll
  for (int e = 0; e < 4; ++e) {
    int c = lane * 4 + e;
    o4[e] = f2bf((v[e] - m) * rs * w[c] + b[c]);
  }
  *(ushort4v*)(t2 + (size_t)row * 256 + lane * 4) = o4;
}

// ---------------------------------------------------------------------------
extern "C" void kernel_launch(void* const* d_in, const int* in_sizes, int n_in,
                              void* d_out, int out_size, void* d_ws, size_t ws_size,
                              hipStream_t stream) {
  const float* x     = (const float*)d_in[0];
  const float* n1w   = (const float*)d_in[1];
  const float* n1b   = (const float*)d_in[2];
  const float* qkvw  = (const float*)d_in[3];
  const float* qkvb  = (const float*)d_in[4];
  const float* projw = (const float*)d_in[5];
  const float* projb = (const float*)d_in[6];
  const float* n2w   = (const float*)d_in[7];
  const float* n2b   = (const float*)d_in[8];
  const float* f1w   = (const float*)d_in[9];
  const float* f1b   = (const float*)d_in[10];
  const float* f2w   = (const float*)d_in[11];
  const float* f2b   = (const float*)d_in[12];

  char* ws = (char*)d_ws;
  // workspace layout (256B-aligned offsets), ~13.8 MB total
  ushort* wcat = (ushort*)(ws + 0);            // 786432 bf16   (1572864 B)
  float*  xT   = (float*)(ws + 1572864);       // 802816 f32    (3211264 B) -> also x1 (in-place resid add)
  ushort* t    = (ushort*)(ws + 4784128);      // 802816 bf16   (1605632 B) t1 then t2
  ushort* qh   = (ushort*)(ws + 6389760);      // qkv [3136][768] then h1 [3136][1024] (6422528 B)
  ushort* attn = (ushort*)(ws + 12812288);     // 802816 bf16   (1605632 B)

  const ushort* qw_bf = wcat;
  const ushort* pw_bf = wcat + 196608;
  const ushort* f1_bf = wcat + 262144;
  const ushort* f2_bf = wcat + 524288;
  float* outf = (float*)d_out;

  hipLaunchKernelGGL(cvt_kernel, dim3(3072), dim3(256), 0, stream,
                     qkvw, projw, f1w, f2w, wcat);
  hipLaunchKernelGGL(ln1_kernel, dim3(196), dim3(256), 0, stream,
                     x, n1w, n1b, xT, t);
  // qkv: [3136,256] @ [768,256]^T
  hipLaunchKernelGGL(gemm_kernel, dim3(12, 49), dim3(256), 0, stream,
                     t, qw_bf, qkvb, (const float*)nullptr,
                     qh, (float*)nullptr, 3136, 768, 256, 0);
  hipLaunchKernelGGL(attn_kernel, dim3(3136), dim3(256), 0, stream, qh, attn);
  // proj: [3136,256] @ [256,256]^T + xT -> x1 (fp32, in-place over xT)
  hipLaunchKernelGGL(gemm_kernel, dim3(4, 49), dim3(256), 0, stream,
                     attn, pw_bf, projb, xT,
                     (ushort*)nullptr, xT, 3136, 256, 256, 1);
  hipLaunchKernelGGL(ln2_kernel, dim3(784), dim3(256), 0, stream,
                     xT, n2w, n2b, t);
  // fc1: [3136,256] @ [1024,256]^T, gelu -> h1
  hipLaunchKernelGGL(gemm_kernel, dim3(16, 49), dim3(256), 0, stream,
                     t, f1_bf, f1b, (const float*)nullptr,
                     qh, (float*)nullptr, 3136, 1024, 256, 2);
  // fc2 (transposed): [256,1024] @ [3136,1024]^T + resid -> d_out [C][N]
  hipLaunchKernelGGL(gemm_kernel, dim3(49, 4), dim3(256), 0, stream,
                     f2_bf, qh, f2b, xT,
                     (ushort*)nullptr, outf, 256, 3136, 1024, 3);
}